// Round 10
// baseline (861.501 us; speedup 1.0000x reference)
//
#include <hip/hip_runtime.h>
#include <math.h>

#define NNODE 100
#define NEGV  -1000000000.0f

// ---------------- static device workspace (ws_size unknown -> avoid d_ws) ---
__device__ float g_Wall [128 * 512];            // [k][c]: Wk^T | Wv^T | G | M^T
__device__ float g_Wall2[128 * 128];            // [k][c]: (Wq@fc1_w)^T
__device__ float g_qcap [128];                  // Wq @ fc_w[:,H]
__device__ float g_C    [(size_t)102400 * 512]; // per (b,n): K|V|K2W|Q1
__device__ float g_qpool[(size_t)1024 * 128];   // per b
__device__ float g_S1   [(size_t)1024 * 100 * 800]; // [b][m][h*100+n]
__device__ float g_Scap [(size_t)1024 * 800];       // [b][h*100+n]

__device__ __forceinline__ float fast_rcp(float x) { return __builtin_amdgcn_rcpf(x); }
__device__ __forceinline__ float tanh10(float z) {
    // 10*tanh(z) = 10 - 20/(exp(2z)+1); exp->inf => 10, exp->0 => -10 (safe)
    const float e2 = __expf(2.0f * z);
    return fmaf(-20.0f, __builtin_amdgcn_rcpf(e2 + 1.0f), 10.0f);
}

// ---- DPP cross-lane (VALU-speed) -------------------------------------------
// quad_perm xor1 = 0xB1, xor2 = 0x4E; row_ror:4 = 0x124, row_ror:8 = 0x128
template<int CTRL>
__device__ __forceinline__ int dpp_i(int v) {
    return __builtin_amdgcn_update_dpp(0, v, CTRL, 0xF, 0xF, true);
}
template<int CTRL>
__device__ __forceinline__ float dpp_f(float v) {
    return __uint_as_float((unsigned)dpp_i<CTRL>(__float_as_int(v)));
}

// ---- xor16 / xor32 butterfly stages ----------------------------------------
// gfx950 permlane16/32_swap builtins (VALU-speed dual-result swap; with
// src=dst=x the two results are x[l&~S] and x[l|S], so sum/max over them is
// the bit-identical butterfly stage). Guarded fallback to LDS-path forms.
#if defined(__has_builtin)
#  if __has_builtin(__builtin_amdgcn_permlane16_swap)
#    define HAVE_PL16 1
#  endif
#  if __has_builtin(__builtin_amdgcn_permlane32_swap)
#    define HAVE_PL32 1
#  endif
#endif

__device__ __forceinline__ void x16_both(float x, float& a, float& b) {
#if defined(HAVE_PL16)
    auto r = __builtin_amdgcn_permlane16_swap(__float_as_uint(x),
                                              __float_as_uint(x), false, false);
    a = __uint_as_float(r[0]); b = __uint_as_float(r[1]);
#else
    a = x;
    b = __uint_as_float(
        (unsigned)__builtin_amdgcn_ds_swizzle(__float_as_int(x), 0x401F));
#endif
}
__device__ __forceinline__ void x32_both(float x, float& a, float& b) {
#if defined(HAVE_PL32)
    auto r = __builtin_amdgcn_permlane32_swap(__float_as_uint(x),
                                              __float_as_uint(x), false, false);
    a = __uint_as_float(r[0]); b = __uint_as_float(r[1]);
#else
    a = x;
    b = __shfl_xor(x, 32, 64);
#endif
}
__device__ __forceinline__ float x16_sum(float x) { float a, b; x16_both(x, a, b); return a + b; }
__device__ __forceinline__ float x16_max(float x) { float a, b; x16_both(x, a, b); return fmaxf(a, b); }
__device__ __forceinline__ float x32_sum(float x) { float a, b; x32_both(x, a, b); return a + b; }
__device__ __forceinline__ float x32_max(float x) { float a, b; x32_both(x, a, b); return fmaxf(a, b); }
// lo = value held by the low 32-lane half (at lane l&31), hi = high half's
__device__ __forceinline__ void x32_pair(float x, float& lo, float& hi) {
#if defined(HAVE_PL32)
    auto r = __builtin_amdgcn_permlane32_swap(__float_as_uint(x),
                                              __float_as_uint(x), false, false);
    lo = __uint_as_float(r[0]); hi = __uint_as_float(r[1]);
#else
    const float o = __shfl_xor(x, 32, 64);
    const bool high = (threadIdx.x & 32) != 0;
    lo = high ? o : x;
    hi = high ? x : o;
#endif
}

// ---------------- kernel 1: fold weights -----------------------------------
__global__ __launch_bounds__(128) void prep_kernel(
    const float* __restrict__ Wk,  const float* __restrict__ Wv,
    const float* __restrict__ Wk2, const float* __restrict__ Wo,
    const float* __restrict__ Wq,  const float* __restrict__ fc_w,
    const float* __restrict__ fc1_w)
{
    const int c = blockIdx.x;
    const int k = threadIdx.x;
    if (c < 128) {
        g_Wall[k * 512 + c] = Wk[c * 128 + k];
    } else if (c < 256) {
        g_Wall[k * 512 + c] = Wv[(c - 128) * 128 + k];
    } else if (c < 384) {                           // G = Wk2^T @ Wo
        const int cc = c - 256;
        float acc = 0.f;
        for (int h = 0; h < 128; h++)
            acc = fmaf(Wk2[h * 128 + k], Wo[h * 128 + cc], acc);
        g_Wall[k * 512 + c] = acc;
    } else if (c < 512) {                           // M^T, M = Wq@fc_w[:,:128]
        const int cc = c - 384;
        float acc = 0.f;
        for (int j = 0; j < 128; j++)
            acc = fmaf(Wq[cc * 128 + j], fc_w[j * 129 + k], acc);
        g_Wall[k * 512 + c] = acc;
    } else if (c == 512) {                          // qcap = Wq @ fc_w[:,128]
        float acc = 0.f;
        for (int j = 0; j < 128; j++)
            acc = fmaf(Wq[k * 128 + j], fc_w[j * 129 + 128], acc);
        g_qcap[k] = acc;
    } else {                                        // (Wq@fc1_w)^T
        const int cc = c - 513;
        float acc = 0.f;
        for (int j = 0; j < 128; j++)
            acc = fmaf(Wq[cc * 128 + j], fc1_w[j * 128 + k], acc);
        g_Wall2[k * 128 + cc] = acc;
    }
}

// ---------------- kernel 2: fp32 tiled GEMM, k-chunked (33 KB LDS) ----------
// 512 threads/block, 8x4/thread, 128x128 block tile; per-output fmaf chain
// k=0..127 sequential -> bit-identical. Mode-1 (pool) folded into grid x>=800.
__global__ __launch_bounds__(512) void gemm_kernel(const float* __restrict__ A0,
                                                   const float* __restrict__ A1)
{
    const bool mode1 = (blockIdx.x >= 800);
    if (mode1 && blockIdx.y > 0) return;
    const float* __restrict__ A = mode1 ? A1 : A0;
    const float* __restrict__ W = mode1 ? g_Wall2 : g_Wall;
    float* __restrict__ C       = mode1 ? g_qpool : g_C;
    const int ncols             = mode1 ? 128 : 512;
    const int m0 = (mode1 ? (blockIdx.x - 800) : blockIdx.x) * 128;
    const int n0 = blockIdx.y * 128;

    __shared__ __align__(16) float At[32 * 132];   // [k_local][m]
    __shared__ __align__(16) float Ws[32 * 128];   // [k_local][n]
    const int tid = threadIdx.x;
    const int tm = tid >> 5, tn = tid & 31;        // tm 0..15
    const int mb = tm * 8, nb = tn * 4;
    float4 acc[8];
#pragma unroll
    for (int i = 0; i < 8; i++) acc[i] = make_float4(0.f, 0.f, 0.f, 0.f);

    for (int kc = 0; kc < 4; kc++) {
        for (int f = tid; f < 1024; f += 512) {
            const int r = f >> 3, q8 = f & 7;
            float4 a = *(const float4*)&A[(size_t)(m0 + r) * 128 + kc * 32 + q8 * 4];
            At[(q8 * 4 + 0) * 132 + r] = a.x;
            At[(q8 * 4 + 1) * 132 + r] = a.y;
            At[(q8 * 4 + 2) * 132 + r] = a.z;
            At[(q8 * 4 + 3) * 132 + r] = a.w;
            const int kl = f >> 5, q = f & 31;
            *(float4*)&Ws[kl * 128 + q * 4] =
                *(const float4*)&W[(size_t)(kc * 32 + kl) * ncols + n0 + q * 4];
        }
        __syncthreads();
        for (int k = 0; k < 32; k++) {
            const float4 w = *(float4*)&Ws[k * 128 + nb];
#pragma unroll
            for (int i = 0; i < 8; i += 4) {
                const float4 a = *(float4*)&At[k * 132 + mb + i];
                acc[i + 0].x = fmaf(a.x, w.x, acc[i + 0].x);
                acc[i + 0].y = fmaf(a.x, w.y, acc[i + 0].y);
                acc[i + 0].z = fmaf(a.x, w.z, acc[i + 0].z);
                acc[i + 0].w = fmaf(a.x, w.w, acc[i + 0].w);
                acc[i + 1].x = fmaf(a.y, w.x, acc[i + 1].x);
                acc[i + 1].y = fmaf(a.y, w.y, acc[i + 1].y);
                acc[i + 1].z = fmaf(a.y, w.z, acc[i + 1].z);
                acc[i + 1].w = fmaf(a.y, w.w, acc[i + 1].w);
                acc[i + 2].x = fmaf(a.z, w.x, acc[i + 2].x);
                acc[i + 2].y = fmaf(a.z, w.y, acc[i + 2].y);
                acc[i + 2].z = fmaf(a.z, w.z, acc[i + 2].z);
                acc[i + 2].w = fmaf(a.z, w.w, acc[i + 2].w);
                acc[i + 3].x = fmaf(a.w, w.x, acc[i + 3].x);
                acc[i + 3].y = fmaf(a.w, w.y, acc[i + 3].y);
                acc[i + 3].z = fmaf(a.w, w.z, acc[i + 3].z);
                acc[i + 3].w = fmaf(a.w, w.w, acc[i + 3].w);
            }
        }
        __syncthreads();
    }
#pragma unroll
    for (int i = 0; i < 8; i++)
        *(float4*)&C[(size_t)(m0 + mb + i) * ncols + n0 + nb] = acc[i];
}

// ---------------- kernel 2.5: per-batch score fold (R9-proven) --------------
// Thread -> 4 consecutive nodes: float4 stores. fmaf chains untouched.
__global__ __launch_bounds__(256) void s1_kernel()
{
    const int b = blockIdx.x;
    const int tid = threadIdx.x;
    const int h = tid >> 5, l32 = tid & 31;
    const int n0 = l32 * 4;                 // 4 consecutive nodes
    const bool act = n0 < 100;              // lanes 0..24
    const float* __restrict__ Crow = &g_C[(size_t)b * 100 * 512];

    __shared__ __align__(16) float Q1sh[50 * 128];   // 25.6 KB

    float4 kr[4][4];                        // [j][i]: K row n0+j, h*16+4i
#pragma unroll
    for (int j = 0; j < 4; j++)
#pragma unroll
        for (int i = 0; i < 4; i++)
            kr[j][i] = act ? *(const float4*)&Crow[(size_t)(n0 + j) * 512 + h * 16 + i * 4]
                           : make_float4(0.f, 0.f, 0.f, 0.f);

    float4 qc[4], qp[4];
#pragma unroll
    for (int i = 0; i < 4; i++) {
        qc[i] = *(const float4*)&g_qcap[h * 16 + i * 4];
        qp[i] = *(const float4*)&g_qpool[(size_t)b * 128 + h * 16 + i * 4];
    }
    float sp[4], scv[4];
#pragma unroll
    for (int j = 0; j < 4; j++) {
        float dc = 0.f, dp = 0.f;
#pragma unroll
        for (int i = 0; i < 4; i++) {
            dc = fmaf(kr[j][i].x, qc[i].x, dc); dc = fmaf(kr[j][i].y, qc[i].y, dc);
            dc = fmaf(kr[j][i].z, qc[i].z, dc); dc = fmaf(kr[j][i].w, qc[i].w, dc);
            dp = fmaf(kr[j][i].x, qp[i].x, dp); dp = fmaf(kr[j][i].y, qp[i].y, dp);
            dp = fmaf(kr[j][i].z, qp[i].z, dp); dp = fmaf(kr[j][i].w, qp[i].w, dp);
        }
        sp[j]  = dp;
        scv[j] = dc * 0.25f;
    }
    if (act)
        *(float4*)&g_Scap[(size_t)b * 800 + h * 100 + n0] =
            make_float4(scv[0], scv[1], scv[2], scv[3]);

    float* __restrict__ S1b = &g_S1[(size_t)b * 80000];
    for (int half = 0; half < 2; half++) {
        const int mbase = half * 50;
        for (int f = tid; f < 1600; f += 256) {        // 50 rows x 32 float4
            const int n = f >> 5, c4 = f & 31;
            *(float4*)&Q1sh[n * 128 + c4 * 4] =
                *(const float4*)&Crow[(size_t)(mbase + n) * 512 + 384 + c4 * 4];
        }
        __syncthreads();
        for (int mm = 0; mm < 50; mm++) {
            const int m = mbase + mm;
            float4 q[4];
#pragma unroll
            for (int i = 0; i < 4; i++)
                q[i] = *(float4*)&Q1sh[mm * 128 + h * 16 + i * 4];
            float dv[4];
#pragma unroll
            for (int j = 0; j < 4; j++) {
                float d = 0.f;
#pragma unroll
                for (int i = 0; i < 4; i++) {
                    d = fmaf(kr[j][i].x, q[i].x, d); d = fmaf(kr[j][i].y, q[i].y, d);
                    d = fmaf(kr[j][i].z, q[i].z, d); d = fmaf(kr[j][i].w, q[i].w, d);
                }
                dv[j] = (d + sp[j]) * 0.25f;
            }
            if (act)
                *(float4*)&S1b[(size_t)m * 800 + h * 100 + n0] =
                    make_float4(dv[0], dv[1], dv[2], dv[3]);
        }
        __syncthreads();   // Q1sh WAR before next half's load
    }
}

// ---------------- kernel 3: decode, TWO batches per 512-thread block ---------
// R10 occupancy probe+win: measured occupancy pinned at 2 workgroups/CU all
// session despite VGPR/LDS/grid allowing 4+. Fusing 2 batches into one
// 512-thread WG doubles waves/WG; if the cap is per-WG-count -> 16 waves/CU.
// Per-thread instruction stream per half is EXACTLY the R9/R4-proven decode
// on its own batch; joint early-exit uses parity-double-buffered done flags
// (write pre-barrier, read post-barrier: race-free, uniform break). A done
// half skips all state-mutating work (provably no-op steps) but keeps hitting
// the shared barriers. NOTE: do NOT reassociate fp sums -- argmax flips.
__global__ __launch_bounds__(512) void decode_kernel(
    const float* __restrict__ capacity, const float* __restrict__ demand,
    const int* __restrict__ nsteps_p, const int* __restrict__ T_p,
    float* __restrict__ out)
{
    __shared__ float u_buf[2][2 * 800];   // [half][parity*800 + r*100 + n]
    __shared__ float demand_sh[2][NNODE];
    __shared__ int   act_sh[2][512];
    __shared__ int   done_sh[2][2];       // [step parity][half]

    const int tid  = threadIdx.x;
    const int half = tid >> 8;            // 0 / 1
    const int htid = tid & 255;           // thread id within half
    const int b    = blockIdx.x * 2 + half;
    const int nsteps = nsteps_p[0];
    const float invT = 1.0f / (float)T_p[0];
    const float base_cap = capacity[0];
    const float inv_sqrt_h = 0.08838834764831845f;  // 1/sqrt(128)

    const float4* __restrict__ C4  = (const float4*)&g_C[(size_t)b * 100 * 512];
    const float*  __restrict__ S1b = &g_S1[(size_t)b * 80000];

    const int w = htid >> 6, l = htid & 63;
    const int g = l >> 3, f = l & 7;
    const int F = 8 * w + f;                   // global float4 col 0..31
    const int h8 = htid >> 5, l32 = htid & 31; // B mapping: head h8, nodes l32+32j

    // ---- persistent registers
    float4 Vreg[13], K2r[13];
#pragma unroll
    for (int m = 0; m < 13; m++) {
        const int n = g + 8 * m;
        const bool v = n < 100;
        Vreg[m] = v ? C4[(size_t)n * 128 + 32 + F] : make_float4(0.f, 0.f, 0.f, 0.f);
        K2r[m]  = v ? C4[(size_t)n * 128 + 64 + F] : make_float4(0.f, 0.f, 0.f, 0.f);
    }
    float s1r[4], scapr[4], d4[4];
#pragma unroll
    for (int j = 0; j < 4; j++) {
        const int nj = l32 + 32 * j;
        const bool v = nj < 100;
        scapr[j] = v ? g_Scap[(size_t)b * 800 + h8 * 100 + nj] : 0.f;
        s1r[j]   = v ? S1b[h8 * 100 + nj] : 0.f;
        d4[j]    = v ? demand[b * 100 + nj] : 1.0e30f;
    }
    const float de0 = demand[b * 100 + l];
    const float de1 = (l + 64 < 100) ? demand[b * 100 + l + 64] : 1.0e30f;
    for (int n = htid; n < 100; n += 256) demand_sh[half][n] = demand[b * 100 + n];
    for (int t = htid; t < 512; t += 256) act_sh[half][t] = 0;  // early-exit backfill
    bool me0 = false, me1 = false;      // mask1 for nodes l, l+64
    unsigned mb4 = 0;                   // mask1 bits for B's 4 nodes
    float cap_r = capacity[b];
    float depot_r;
    {
        const bool am0 = (l == 0) ? true : (de0 > cap_r);
        const bool am1 = (l + 64 >= 100) ? true : (de1 > cap_r);
        depot_r = __all(am0 && am1) ? 0.f : 1.f;
    }
    float logp_r = 0.f;
    int visited_r = 0;
    int ub = 0;
    __syncthreads();

    for (int s = 0; s < nsteps; s++) {
        const bool myDone = (visited_r >= 99);   // uniform within half
        if (htid == 0) done_sh[s & 1][half] = myDone ? 1 : 0;

        const float cap = cap_r;
        float v0, v1 = -3.0e38f;

        if (!myDone) {
            // ---- B: masked scores + raw exp (no max-sub; masked -> exp = 0)
            float a[4];
            float tot;
            {
                float sc[4];
#pragma unroll
                for (int j = 0; j < 4; j++) {
                    const int nj = l32 + 32 * j;
                    const bool m = (nj == 0) ? (depot_r != 0.f)
                        : (((mb4 >> j) & 1u) || (d4[j] > cap));
                    const float raw = fmaf(cap, scapr[j], s1r[j]);
                    sc[j] = (nj < 100 && !m) ? raw : NEGV;
                }
#pragma unroll
                for (int j = 0; j < 4; j++) a[j] = __expf(sc[j]);
                tot = (a[0] + a[1]) + (a[2] + a[3]);
            }

            // ---- C: glimpse cols 4F..4F+3 (unnormalized attn via shfl)
            float4 gp4 = make_float4(0.f, 0.f, 0.f, 0.f);
#pragma unroll
            for (int m = 0; m < 13; m++) {
                const int src = ((f >> 2) << 5) | (8 * (m & 3) + g);
                const float av = __shfl(a[m >> 2], src, 64);
                gp4.x = fmaf(av, Vreg[m].x, gp4.x);
                gp4.y = fmaf(av, Vreg[m].y, gp4.y);
                gp4.z = fmaf(av, Vreg[m].z, gp4.z);
                gp4.w = fmaf(av, Vreg[m].w, gp4.w);
            }
            // tot: quad xor1,xor2 + ror4,ror8 (DPP) + xor16 (permlane, VALU)
            tot += dpp_f<0xB1>(tot);
            tot += dpp_f<0x4E>(tot);
            tot += dpp_f<0x124>(tot);
            tot += dpp_f<0x128>(tot);
            tot = x16_sum(tot);
            // gp butterfly: xor8 (DPP ror8), xor16/xor32 permlane
            gp4.x += dpp_f<0x128>(gp4.x);
            gp4.y += dpp_f<0x128>(gp4.y);
            gp4.z += dpp_f<0x128>(gp4.z);
            gp4.w += dpp_f<0x128>(gp4.w);
            gp4.x = x16_sum(gp4.x);
            gp4.y = x16_sum(gp4.y);
            gp4.z = x16_sum(gp4.z);
            gp4.w = x16_sum(gp4.w);
            gp4.x = x32_sum(gp4.x);
            gp4.y = x32_sum(gp4.y);
            gp4.z = x32_sum(gp4.z);
            gp4.w = x32_sum(gp4.w);
            // normalize by this col's head-tot (head of col F = 2w + (f>>2))
            {
                float tlo, thi;
                x32_pair(tot, tlo, thi);
                const float th = (f >> 2) ? thi : tlo;
                const float rt = fast_rcp(th);
                gp4.x *= rt; gp4.y *= rt; gp4.z *= rt; gp4.w *= rt;
            }

            // ---- U: u-partials over this wave's 32 cols -> rows 2w,2w+1
            {
                float pm[13];
#pragma unroll
                for (int m = 0; m < 13; m++) {
                    float p = gp4.x * K2r[m].x;
                    p = fmaf(gp4.y, K2r[m].y, p);
                    p = fmaf(gp4.z, K2r[m].z, p);
                    p = fmaf(gp4.w, K2r[m].w, p);
                    pm[m] = p;
                }
#pragma unroll
                for (int m = 0; m < 13; m++) pm[m] += dpp_f<0xB1>(pm[m]);
#pragma unroll
                for (int m = 0; m < 13; m++) pm[m] += dpp_f<0x4E>(pm[m]);
                if ((f & 3) == 0) {
                    const int r = w * 2 + (f >> 2);
#pragma unroll
                    for (int m = 0; m < 13; m++) {
                        const int n = g + 8 * m;
                        if (n < 100) u_buf[half][ub + r * 100 + n] = pm[m];
                    }
                }
            }
        }
        __syncthreads();

        // uniform across the whole block: both halves done -> stop (remaining
        // steps provably emit idx=0 / frozen logp for both; act_sh pre-zeroed)
        if (done_sh[s & 1][0] && done_sh[s & 1][1]) break;

        if (!myDone) {
            // ---- E: ALL waves of this half redundantly -- argmax + lse
            {
                float s8 = 0.f;
#pragma unroll
                for (int r = 0; r < 8; r++) s8 += u_buf[half][ub + r * 100 + l];
                const float u0 = tanh10(s8 * inv_sqrt_h);
                const bool m0 = (l == 0) ? (depot_r != 0.f) : (me0 || de0 > cap);
                v0 = (m0 ? NEGV : u0) * invT;
                if (l + 64 < 100) {
                    float t8 = 0.f;
#pragma unroll
                    for (int r = 0; r < 8; r++) t8 += u_buf[half][ub + r * 100 + l + 64];
                    const float u1 = tanh10(t8 * inv_sqrt_h);
                    const bool m1 = (me1 || de1 > cap);
                    v1 = (m1 ? NEGV : u1) * invT;
                }
            }
            float tt = __expf(v0) + ((l + 64 < 100) ? __expf(v1) : 0.f);
            float vm = fmaxf(v0, v1);
#define E_STG(CTRL)                                                           \
            {                                                                 \
                tt += dpp_f<CTRL>(tt);                                        \
                vm = fmaxf(vm, dpp_f<CTRL>(vm));                              \
            }
            E_STG(0xB1)
            E_STG(0x4E)
            E_STG(0x124)
            E_STG(0x128)
#undef E_STG
            tt = x16_sum(tt);                       // exact xor16 (VALU)
            vm = x16_max(vm);
            tt = x32_sum(tt);                       // exact xor32 (VALU)
            vm = x32_max(vm);
            // ballot argmax (ties impossible: masked=-1e9, valid in (-10,10))
            const unsigned long long b0 = __ballot(v0 == vm);
            const unsigned long long b1 = __ballot(v1 == vm);
            const int idx = b0 ? (int)__builtin_ctzll(b0)
                               : (64 + (int)__builtin_ctzll(b1));

            // prefetch next S1 row ASAP (state-update ops hide the load)
#pragma unroll
            for (int j = 0; j < 4; j++) {
                const int nj = l32 + 32 * j;
                if (nj < 100)
                    s1r[j] = S1b[(size_t)idx * 800 + h8 * 100 + nj];
            }

            const float dmd_idx = demand_sh[half][idx];  // uniform -> broadcast
            const float capn = (idx == 0) ? base_cap : (cap - dmd_idx);

            if (visited_r < 99) logp_r += vm - __logf(tt);
            visited_r += (idx > 0) ? 1 : 0;
            me0 = me0 || (l == idx && idx > 0);
            me1 = me1 || (l + 64 == idx);
#pragma unroll
            for (int j = 0; j < 4; j++)
                if ((l32 + 32 * j) == idx && idx > 0) mb4 |= (1u << j);

            const bool am0 = (l == 0) ? true : (me0 || de0 > capn);
            const bool am1 = (l + 64 >= 100) ? true : (me1 || de1 > capn);
            const bool allc = __all(am0 && am1);
            depot_r = allc ? 0.f : ((idx == 0) ? 1.f : 0.f);
            cap_r = capn;
            if (htid == 0) act_sh[half][s] = idx;
            ub ^= 800;
        }
    }

    __syncthreads();
    const size_t NB = (size_t)gridDim.x * 2;
    for (int t = htid; t < nsteps; t += 256)
        out[(size_t)b * nsteps + t] = (float)act_sh[half][t];
    if (htid == 0)
        out[NB * nsteps + b] = logp_r;
}

// ---------------- launcher ---------------------------------------------------
extern "C" void kernel_launch(void* const* d_in, const int* in_sizes, int n_in,
                              void* d_out, int out_size, void* d_ws, size_t ws_size,
                              hipStream_t stream) {
    const float* enc    = (const float*)d_in[0];
    const float* pool   = (const float*)d_in[1];
    const float* cap    = (const float*)d_in[2];
    const float* demand = (const float*)d_in[3];
    const float* fc_w   = (const float*)d_in[4];
    const float* fc1_w  = (const float*)d_in[5];
    const float* Wq     = (const float*)d_in[6];
    const float* Wk     = (const float*)d_in[7];
    const float* Wv     = (const float*)d_in[8];
    const float* Wo     = (const float*)d_in[9];
    const float* Wk2    = (const float*)d_in[10];
    const int*   nst    = (const int*)d_in[11];
    const int*   Tp     = (const int*)d_in[12];
    float* out = (float*)d_out;

    prep_kernel<<<641, 128, 0, stream>>>(Wk, Wv, Wk2, Wo, Wq, fc_w, fc1_w);
    gemm_kernel<<<dim3(808, 4), 512, 0, stream>>>(enc, pool);   // mode1 folded in
    s1_kernel<<<1024, 256, 0, stream>>>();
    decode_kernel<<<512, 512, 0, stream>>>(cap, demand, nst, Tp, out);
}

// Round 11
// 810.485 us; speedup vs baseline: 1.0629x; 1.0629x over previous
//
#include <hip/hip_runtime.h>
#include <math.h>

#define NNODE 100
#define NEGV  -1000000000.0f

// ---------------- static device workspace (ws_size unknown -> avoid d_ws) ---
__device__ float g_Wall [128 * 512];            // [k][c]: Wk^T | Wv^T | G | M^T
__device__ float g_Wall2[128 * 128];            // [k][c]: (Wq@fc1_w)^T
__device__ float g_qcap [128];                  // Wq @ fc_w[:,H]
__device__ float g_C    [(size_t)102400 * 512]; // per (b,n): K|V|K2W|Q1
__device__ float g_qpool[(size_t)1024 * 128];   // per b
__device__ float g_S1   [(size_t)1024 * 100 * 800]; // [b][m][h*100+n]
__device__ float g_Scap [(size_t)1024 * 800];       // [b][h*100+n]

__device__ __forceinline__ float fast_rcp(float x) { return __builtin_amdgcn_rcpf(x); }
__device__ __forceinline__ float tanh10(float z) {
    // 10*tanh(z) = 10 - 20/(exp(2z)+1); exp->inf => 10, exp->0 => -10 (safe)
    const float e2 = __expf(2.0f * z);
    return fmaf(-20.0f, __builtin_amdgcn_rcpf(e2 + 1.0f), 10.0f);
}

// ---- DPP cross-lane (VALU-speed) -------------------------------------------
// quad_perm xor1 = 0xB1, xor2 = 0x4E; row_ror:4 = 0x124, row_ror:8 = 0x128
template<int CTRL>
__device__ __forceinline__ int dpp_i(int v) {
    return __builtin_amdgcn_update_dpp(0, v, CTRL, 0xF, 0xF, true);
}
template<int CTRL>
__device__ __forceinline__ float dpp_f(float v) {
    return __uint_as_float((unsigned)dpp_i<CTRL>(__float_as_int(v)));
}

// ---- xor16 / xor32 butterfly stages ----------------------------------------
// gfx950 permlane16/32_swap builtins (VALU-speed dual-result swap; with
// src=dst=x the two results are x[l&~S] and x[l|S], so sum/max over them is
// the bit-identical butterfly stage). Guarded fallback to LDS-path forms.
#if defined(__has_builtin)
#  if __has_builtin(__builtin_amdgcn_permlane16_swap)
#    define HAVE_PL16 1
#  endif
#  if __has_builtin(__builtin_amdgcn_permlane32_swap)
#    define HAVE_PL32 1
#  endif
#endif

__device__ __forceinline__ void x16_both(float x, float& a, float& b) {
#if defined(HAVE_PL16)
    auto r = __builtin_amdgcn_permlane16_swap(__float_as_uint(x),
                                              __float_as_uint(x), false, false);
    a = __uint_as_float(r[0]); b = __uint_as_float(r[1]);
#else
    a = x;
    b = __uint_as_float(
        (unsigned)__builtin_amdgcn_ds_swizzle(__float_as_int(x), 0x401F));
#endif
}
__device__ __forceinline__ void x32_both(float x, float& a, float& b) {
#if defined(HAVE_PL32)
    auto r = __builtin_amdgcn_permlane32_swap(__float_as_uint(x),
                                              __float_as_uint(x), false, false);
    a = __uint_as_float(r[0]); b = __uint_as_float(r[1]);
#else
    a = x;
    b = __shfl_xor(x, 32, 64);
#endif
}
__device__ __forceinline__ float x16_sum(float x) { float a, b; x16_both(x, a, b); return a + b; }
__device__ __forceinline__ float x16_max(float x) { float a, b; x16_both(x, a, b); return fmaxf(a, b); }
__device__ __forceinline__ float x32_sum(float x) { float a, b; x32_both(x, a, b); return a + b; }
__device__ __forceinline__ float x32_max(float x) { float a, b; x32_both(x, a, b); return fmaxf(a, b); }
// lo = value held by the low 32-lane half (at lane l&31), hi = high half's
__device__ __forceinline__ void x32_pair(float x, float& lo, float& hi) {
#if defined(HAVE_PL32)
    auto r = __builtin_amdgcn_permlane32_swap(__float_as_uint(x),
                                              __float_as_uint(x), false, false);
    lo = __uint_as_float(r[0]); hi = __uint_as_float(r[1]);
#else
    const float o = __shfl_xor(x, 32, 64);
    const bool high = (threadIdx.x & 32) != 0;
    lo = high ? o : x;
    hi = high ? x : o;
#endif
}

// ---------------- kernel 1: fold weights -----------------------------------
__global__ __launch_bounds__(128) void prep_kernel(
    const float* __restrict__ Wk,  const float* __restrict__ Wv,
    const float* __restrict__ Wk2, const float* __restrict__ Wo,
    const float* __restrict__ Wq,  const float* __restrict__ fc_w,
    const float* __restrict__ fc1_w)
{
    const int c = blockIdx.x;
    const int k = threadIdx.x;
    if (c < 128) {
        g_Wall[k * 512 + c] = Wk[c * 128 + k];
    } else if (c < 256) {
        g_Wall[k * 512 + c] = Wv[(c - 128) * 128 + k];
    } else if (c < 384) {                           // G = Wk2^T @ Wo
        const int cc = c - 256;
        float acc = 0.f;
        for (int h = 0; h < 128; h++)
            acc = fmaf(Wk2[h * 128 + k], Wo[h * 128 + cc], acc);
        g_Wall[k * 512 + c] = acc;
    } else if (c < 512) {                           // M^T, M = Wq@fc_w[:,:128]
        const int cc = c - 384;
        float acc = 0.f;
        for (int j = 0; j < 128; j++)
            acc = fmaf(Wq[cc * 128 + j], fc_w[j * 129 + k], acc);
        g_Wall[k * 512 + c] = acc;
    } else if (c == 512) {                          // qcap = Wq @ fc_w[:,128]
        float acc = 0.f;
        for (int j = 0; j < 128; j++)
            acc = fmaf(Wq[k * 128 + j], fc_w[j * 129 + 128], acc);
        g_qcap[k] = acc;
    } else {                                        // (Wq@fc1_w)^T
        const int cc = c - 513;
        float acc = 0.f;
        for (int j = 0; j < 128; j++)
            acc = fmaf(Wq[cc * 128 + j], fc1_w[j * 128 + k], acc);
        g_Wall2[k * 128 + cc] = acc;
    }
}

// ---------------- kernel 2: fp32 tiled GEMM, k-chunked (33 KB LDS) ----------
// 512 threads/block, 8x4/thread, 128x128 block tile; per-output fmaf chain
// k=0..127 sequential -> bit-identical. Mode-1 (pool) folded into grid x>=800.
__global__ __launch_bounds__(512) void gemm_kernel(const float* __restrict__ A0,
                                                   const float* __restrict__ A1)
{
    const bool mode1 = (blockIdx.x >= 800);
    if (mode1 && blockIdx.y > 0) return;
    const float* __restrict__ A = mode1 ? A1 : A0;
    const float* __restrict__ W = mode1 ? g_Wall2 : g_Wall;
    float* __restrict__ C       = mode1 ? g_qpool : g_C;
    const int ncols             = mode1 ? 128 : 512;
    const int m0 = (mode1 ? (blockIdx.x - 800) : blockIdx.x) * 128;
    const int n0 = blockIdx.y * 128;

    __shared__ __align__(16) float At[32 * 132];   // [k_local][m]
    __shared__ __align__(16) float Ws[32 * 128];   // [k_local][n]
    const int tid = threadIdx.x;
    const int tm = tid >> 5, tn = tid & 31;        // tm 0..15
    const int mb = tm * 8, nb = tn * 4;
    float4 acc[8];
#pragma unroll
    for (int i = 0; i < 8; i++) acc[i] = make_float4(0.f, 0.f, 0.f, 0.f);

    for (int kc = 0; kc < 4; kc++) {
        for (int f = tid; f < 1024; f += 512) {
            const int r = f >> 3, q8 = f & 7;
            float4 a = *(const float4*)&A[(size_t)(m0 + r) * 128 + kc * 32 + q8 * 4];
            At[(q8 * 4 + 0) * 132 + r] = a.x;
            At[(q8 * 4 + 1) * 132 + r] = a.y;
            At[(q8 * 4 + 2) * 132 + r] = a.z;
            At[(q8 * 4 + 3) * 132 + r] = a.w;
            const int kl = f >> 5, q = f & 31;
            *(float4*)&Ws[kl * 128 + q * 4] =
                *(const float4*)&W[(size_t)(kc * 32 + kl) * ncols + n0 + q * 4];
        }
        __syncthreads();
        for (int k = 0; k < 32; k++) {
            const float4 w = *(float4*)&Ws[k * 128 + nb];
#pragma unroll
            for (int i = 0; i < 8; i += 4) {
                const float4 a = *(float4*)&At[k * 132 + mb + i];
                acc[i + 0].x = fmaf(a.x, w.x, acc[i + 0].x);
                acc[i + 0].y = fmaf(a.x, w.y, acc[i + 0].y);
                acc[i + 0].z = fmaf(a.x, w.z, acc[i + 0].z);
                acc[i + 0].w = fmaf(a.x, w.w, acc[i + 0].w);
                acc[i + 1].x = fmaf(a.y, w.x, acc[i + 1].x);
                acc[i + 1].y = fmaf(a.y, w.y, acc[i + 1].y);
                acc[i + 1].z = fmaf(a.y, w.z, acc[i + 1].z);
                acc[i + 1].w = fmaf(a.y, w.w, acc[i + 1].w);
                acc[i + 2].x = fmaf(a.z, w.x, acc[i + 2].x);
                acc[i + 2].y = fmaf(a.z, w.y, acc[i + 2].y);
                acc[i + 2].z = fmaf(a.z, w.z, acc[i + 2].z);
                acc[i + 2].w = fmaf(a.z, w.w, acc[i + 2].w);
                acc[i + 3].x = fmaf(a.w, w.x, acc[i + 3].x);
                acc[i + 3].y = fmaf(a.w, w.y, acc[i + 3].y);
                acc[i + 3].z = fmaf(a.w, w.z, acc[i + 3].z);
                acc[i + 3].w = fmaf(a.w, w.w, acc[i + 3].w);
            }
        }
        __syncthreads();
    }
#pragma unroll
    for (int i = 0; i < 8; i++)
        *(float4*)&C[(size_t)(m0 + mb + i) * ncols + n0 + nb] = acc[i];
}

// ---------------- kernel 2.5: per-batch score fold (R9-proven) --------------
// Thread -> 4 consecutive nodes: float4 stores. fmaf chains untouched.
__global__ __launch_bounds__(256) void s1_kernel()
{
    const int b = blockIdx.x;
    const int tid = threadIdx.x;
    const int h = tid >> 5, l32 = tid & 31;
    const int n0 = l32 * 4;                 // 4 consecutive nodes
    const bool act = n0 < 100;              // lanes 0..24
    const float* __restrict__ Crow = &g_C[(size_t)b * 100 * 512];

    __shared__ __align__(16) float Q1sh[50 * 128];   // 25.6 KB

    float4 kr[4][4];                        // [j][i]: K row n0+j, h*16+4i
#pragma unroll
    for (int j = 0; j < 4; j++)
#pragma unroll
        for (int i = 0; i < 4; i++)
            kr[j][i] = act ? *(const float4*)&Crow[(size_t)(n0 + j) * 512 + h * 16 + i * 4]
                           : make_float4(0.f, 0.f, 0.f, 0.f);

    float4 qc[4], qp[4];
#pragma unroll
    for (int i = 0; i < 4; i++) {
        qc[i] = *(const float4*)&g_qcap[h * 16 + i * 4];
        qp[i] = *(const float4*)&g_qpool[(size_t)b * 128 + h * 16 + i * 4];
    }
    float sp[4], scv[4];
#pragma unroll
    for (int j = 0; j < 4; j++) {
        float dc = 0.f, dp = 0.f;
#pragma unroll
        for (int i = 0; i < 4; i++) {
            dc = fmaf(kr[j][i].x, qc[i].x, dc); dc = fmaf(kr[j][i].y, qc[i].y, dc);
            dc = fmaf(kr[j][i].z, qc[i].z, dc); dc = fmaf(kr[j][i].w, qc[i].w, dc);
            dp = fmaf(kr[j][i].x, qp[i].x, dp); dp = fmaf(kr[j][i].y, qp[i].y, dp);
            dp = fmaf(kr[j][i].z, qp[i].z, dp); dp = fmaf(kr[j][i].w, qp[i].w, dp);
        }
        sp[j]  = dp;
        scv[j] = dc * 0.25f;
    }
    if (act)
        *(float4*)&g_Scap[(size_t)b * 800 + h * 100 + n0] =
            make_float4(scv[0], scv[1], scv[2], scv[3]);

    float* __restrict__ S1b = &g_S1[(size_t)b * 80000];
    for (int half = 0; half < 2; half++) {
        const int mbase = half * 50;
        for (int f = tid; f < 1600; f += 256) {        // 50 rows x 32 float4
            const int n = f >> 5, c4 = f & 31;
            *(float4*)&Q1sh[n * 128 + c4 * 4] =
                *(const float4*)&Crow[(size_t)(mbase + n) * 512 + 384 + c4 * 4];
        }
        __syncthreads();
        for (int mm = 0; mm < 50; mm++) {
            const int m = mbase + mm;
            float4 q[4];
#pragma unroll
            for (int i = 0; i < 4; i++)
                q[i] = *(float4*)&Q1sh[mm * 128 + h * 16 + i * 4];
            float dv[4];
#pragma unroll
            for (int j = 0; j < 4; j++) {
                float d = 0.f;
#pragma unroll
                for (int i = 0; i < 4; i++) {
                    d = fmaf(kr[j][i].x, q[i].x, d); d = fmaf(kr[j][i].y, q[i].y, d);
                    d = fmaf(kr[j][i].z, q[i].z, d); d = fmaf(kr[j][i].w, q[i].w, d);
                }
                dv[j] = (d + sp[j]) * 0.25f;
            }
            if (act)
                *(float4*)&S1b[(size_t)m * 800 + h * 100 + n0] =
                    make_float4(dv[0], dv[1], dv[2], dv[3]);
        }
        __syncthreads();   // Q1sh WAR before next half's load
    }
}

// ---------------- kernel 3: sequential decode (R9-proven best, 461us) --------
// 256 threads, one batch per block. S1 precomputed + streamed from HBM with
// prefetch issued right after idx. Structural-attack ledger: serial-E x,
// permlane OK, K-in-LDS x (occ halved), K-recompute-global x (serial chain),
// setprio x (-5%), 2-batch WG fusion x (+66us: residency invariant at
// ~8 waves/CU regardless of WG shape). All-wave redundant E in the latency
// shadow; permlane butterflies; ballot argmax; early-exit.
// NOTE: do NOT reassociate fp sums -- ~1ulp can flip an argmax.
__global__ __launch_bounds__(256) void decode_kernel(
    const float* __restrict__ capacity, const float* __restrict__ demand,
    const int* __restrict__ nsteps_p, const int* __restrict__ T_p,
    float* __restrict__ out)
{
    __shared__ float u_buf[2 * 800];    // [parity][r<8][n<100]
    __shared__ float demand_sh[NNODE];
    __shared__ int   act_sh[512];

    const int tid = threadIdx.x;
    const int b   = blockIdx.x;
    const int nsteps = nsteps_p[0];
    const float invT = 1.0f / (float)T_p[0];
    const float base_cap = capacity[0];
    const float inv_sqrt_h = 0.08838834764831845f;  // 1/sqrt(128)

    const float4* __restrict__ C4  = (const float4*)&g_C[(size_t)b * 100 * 512];
    const float*  __restrict__ S1b = &g_S1[(size_t)b * 80000];

    const int w = tid >> 6, l = tid & 63;
    const int g = l >> 3, f = l & 7;
    const int F = 8 * w + f;                 // global float4 col 0..31
    const int h8 = tid >> 5, l32 = tid & 31; // B mapping: head h8, nodes l32+32j

    // ---- persistent registers
    float4 Vreg[13], K2r[13];
#pragma unroll
    for (int m = 0; m < 13; m++) {
        const int n = g + 8 * m;
        const bool v = n < 100;
        Vreg[m] = v ? C4[(size_t)n * 128 + 32 + F] : make_float4(0.f, 0.f, 0.f, 0.f);
        K2r[m]  = v ? C4[(size_t)n * 128 + 64 + F] : make_float4(0.f, 0.f, 0.f, 0.f);
    }
    float s1r[4], scapr[4], d4[4];
#pragma unroll
    for (int j = 0; j < 4; j++) {
        const int nj = l32 + 32 * j;
        const bool v = nj < 100;
        scapr[j] = v ? g_Scap[(size_t)b * 800 + h8 * 100 + nj] : 0.f;
        s1r[j]   = v ? S1b[h8 * 100 + nj] : 0.f;
        d4[j]    = v ? demand[b * 100 + nj] : 1.0e30f;
    }
    const float de0 = demand[b * 100 + l];
    const float de1 = (l + 64 < 100) ? demand[b * 100 + l + 64] : 1.0e30f;
    for (int n = tid; n < 100; n += 256) demand_sh[n] = demand[b * 100 + n];
    for (int t = tid; t < 512; t += 256) act_sh[t] = 0;   // early-exit backfill
    bool me0 = false, me1 = false;      // mask1 for nodes l, l+64
    unsigned mb4 = 0;                   // mask1 bits for B's 4 nodes
    float cap_r = capacity[b];
    float depot_r;
    {
        const bool am0 = (l == 0) ? true : (de0 > cap_r);
        const bool am1 = (l + 64 >= 100) ? true : (de1 > cap_r);
        depot_r = __all(am0 && am1) ? 0.f : 1.f;
    }
    float logp_r = 0.f;
    int visited_r = 0;
    int ub = 0;
    __syncthreads();

    for (int s = 0; s < nsteps; s++) {
        const float cap = cap_r;

        // ---- B: masked scores + raw exp (no max-sub; masked -> exp = 0)
        float a[4];
        float tot;
        {
            float sc[4];
#pragma unroll
            for (int j = 0; j < 4; j++) {
                const int nj = l32 + 32 * j;
                const bool m = (nj == 0) ? (depot_r != 0.f)
                    : (((mb4 >> j) & 1u) || (d4[j] > cap));
                const float raw = fmaf(cap, scapr[j], s1r[j]);
                sc[j] = (nj < 100 && !m) ? raw : NEGV;
            }
#pragma unroll
            for (int j = 0; j < 4; j++) a[j] = __expf(sc[j]);
            tot = (a[0] + a[1]) + (a[2] + a[3]);
        }

        // ---- C: glimpse cols 4F..4F+3 (unnormalized attn via shfl); the
        //      width-32 tot reduction overlaps the shfl chain
        float4 gp4 = make_float4(0.f, 0.f, 0.f, 0.f);
#pragma unroll
        for (int m = 0; m < 13; m++) {
            const int src = ((f >> 2) << 5) | (8 * (m & 3) + g);
            const float av = __shfl(a[m >> 2], src, 64);
            gp4.x = fmaf(av, Vreg[m].x, gp4.x);
            gp4.y = fmaf(av, Vreg[m].y, gp4.y);
            gp4.z = fmaf(av, Vreg[m].z, gp4.z);
            gp4.w = fmaf(av, Vreg[m].w, gp4.w);
        }
        // tot: quad xor1,xor2 + ror4,ror8 (DPP) + xor16 (permlane, VALU)
        tot += dpp_f<0xB1>(tot);
        tot += dpp_f<0x4E>(tot);
        tot += dpp_f<0x124>(tot);
        tot += dpp_f<0x128>(tot);
        tot = x16_sum(tot);
        // gp butterfly: xor8 via row_ror:8 (exact DPP), xor16/xor32 permlane
        gp4.x += dpp_f<0x128>(gp4.x);
        gp4.y += dpp_f<0x128>(gp4.y);
        gp4.z += dpp_f<0x128>(gp4.z);
        gp4.w += dpp_f<0x128>(gp4.w);
        gp4.x = x16_sum(gp4.x);
        gp4.y = x16_sum(gp4.y);
        gp4.z = x16_sum(gp4.z);
        gp4.w = x16_sum(gp4.w);
        gp4.x = x32_sum(gp4.x);
        gp4.y = x32_sum(gp4.y);
        gp4.z = x32_sum(gp4.z);
        gp4.w = x32_sum(gp4.w);
        // normalize by this col's head-tot (head of col F = 2w + (f>>2))
        {
            float tlo, thi;
            x32_pair(tot, tlo, thi);
            const float th = (f >> 2) ? thi : tlo;
            const float rt = fast_rcp(th);
            gp4.x *= rt; gp4.y *= rt; gp4.z *= rt; gp4.w *= rt;
        }

        // ---- U: u-partials over this wave's 32 cols -> u_buf rows 2w,2w+1
        {
            float pm[13];
#pragma unroll
            for (int m = 0; m < 13; m++) {
                float p = gp4.x * K2r[m].x;
                p = fmaf(gp4.y, K2r[m].y, p);
                p = fmaf(gp4.z, K2r[m].z, p);
                p = fmaf(gp4.w, K2r[m].w, p);
                pm[m] = p;
            }
#pragma unroll
            for (int m = 0; m < 13; m++) pm[m] += dpp_f<0xB1>(pm[m]);  // xor1
#pragma unroll
            for (int m = 0; m < 13; m++) pm[m] += dpp_f<0x4E>(pm[m]);  // xor2
            if ((f & 3) == 0) {
                const int r = w * 2 + (f >> 2);
#pragma unroll
                for (int m = 0; m < 13; m++) {
                    const int n = g + 8 * m;
                    if (n < 100) u_buf[ub + r * 100 + n] = pm[m];
                }
            }
        }
        __syncthreads();

        // ---- E: ALL waves redundantly (fits in latency shadow; no 2nd
        //      barrier, no broadcast) -- fused argmax + lse, ballot argmax
        float v0, v1 = -3.0e38f;
        {
            float s8 = 0.f;
#pragma unroll
            for (int r = 0; r < 8; r++) s8 += u_buf[ub + r * 100 + l];
            const float u0 = tanh10(s8 * inv_sqrt_h);
            const bool m0 = (l == 0) ? (depot_r != 0.f) : (me0 || de0 > cap);
            v0 = (m0 ? NEGV : u0) * invT;
            if (l + 64 < 100) {
                float t8 = 0.f;
#pragma unroll
                for (int r = 0; r < 8; r++) t8 += u_buf[ub + r * 100 + l + 64];
                const float u1 = tanh10(t8 * inv_sqrt_h);
                const bool m1 = (me1 || de1 > cap);
                v1 = (m1 ? NEGV : u1) * invT;
            }
        }
        float tt = __expf(v0) + ((l + 64 < 100) ? __expf(v1) : 0.f);
        float vm = fmaxf(v0, v1);
#define E_STG(CTRL)                                                           \
        {                                                                     \
            tt += dpp_f<CTRL>(tt);                                            \
            vm = fmaxf(vm, dpp_f<CTRL>(vm));                                  \
        }
        E_STG(0xB1)
        E_STG(0x4E)
        E_STG(0x124)
        E_STG(0x128)
#undef E_STG
        tt = x16_sum(tt);                       // exact xor16 (VALU)
        vm = x16_max(vm);
        tt = x32_sum(tt);                       // exact xor32 (VALU)
        vm = x32_max(vm);
        // argmax via ballot: max is exact selection -> bitwise equality;
        // lowest index on (impossible) ties matches jnp.argmax first-occur.
        const unsigned long long b0 = __ballot(v0 == vm);
        const unsigned long long b1 = __ballot(v1 == vm);
        const int idx = b0 ? (int)__builtin_ctzll(b0)
                           : (64 + (int)__builtin_ctzll(b1));

        // prefetch next S1 row ASAP (state-update ops hide part of the load)
#pragma unroll
        for (int j = 0; j < 4; j++) {
            const int nj = l32 + 32 * j;
            if (nj < 100)
                s1r[j] = S1b[(size_t)idx * 800 + h8 * 100 + nj];
        }

        const float dmd_idx = demand_sh[idx];       // uniform addr -> broadcast
        const float capn = (idx == 0) ? base_cap : (cap - dmd_idx);

        if (visited_r < 99) logp_r += vm - __logf(tt);
        visited_r += (idx > 0) ? 1 : 0;
        me0 = me0 || (l == idx && idx > 0);
        me1 = me1 || (l + 64 == idx);
#pragma unroll
        for (int j = 0; j < 4; j++)
            if ((l32 + 32 * j) == idx && idx > 0) mb4 |= (1u << j);

        const bool am0 = (l == 0) ? true : (me0 || de0 > capn);
        const bool am1 = (l + 64 >= 100) ? true : (me1 || de1 > capn);
        const bool allc = __all(am0 && am1);
        depot_r = allc ? 0.f : ((idx == 0) ? 1.f : 0.f);
        cap_r = capn;
        if (tid == 0) act_sh[s] = idx;
        ub ^= 800;

        // all 99 customers visited -> remaining steps provably emit idx=0
        // (act_sh pre-zeroed) and logp frozen: stop.
        if (visited_r >= 99) break;
    }

    __syncthreads();
    for (int t = tid; t < nsteps; t += 256)
        out[(size_t)b * nsteps + t] = (float)act_sh[t];
    if (tid == 0)
        out[(size_t)gridDim.x * nsteps + b] = logp_r;
}

// ---------------- launcher ---------------------------------------------------
extern "C" void kernel_launch(void* const* d_in, const int* in_sizes, int n_in,
                              void* d_out, int out_size, void* d_ws, size_t ws_size,
                              hipStream_t stream) {
    const float* enc    = (const float*)d_in[0];
    const float* pool   = (const float*)d_in[1];
    const float* cap    = (const float*)d_in[2];
    const float* demand = (const float*)d_in[3];
    const float* fc_w   = (const float*)d_in[4];
    const float* fc1_w  = (const float*)d_in[5];
    const float* Wq     = (const float*)d_in[6];
    const float* Wk     = (const float*)d_in[7];
    const float* Wv     = (const float*)d_in[8];
    const float* Wo     = (const float*)d_in[9];
    const float* Wk2    = (const float*)d_in[10];
    const int*   nst    = (const int*)d_in[11];
    const int*   Tp     = (const int*)d_in[12];
    float* out = (float*)d_out;

    prep_kernel<<<641, 128, 0, stream>>>(Wk, Wv, Wk2, Wo, Wq, fc_w, fc1_w);
    gemm_kernel<<<dim3(808, 4), 512, 0, stream>>>(enc, pool);   // mode1 folded in
    s1_kernel<<<1024, 256, 0, stream>>>();
    decode_kernel<<<1024, 256, 0, stream>>>(cap, demand, nst, Tp, out);
}